// Round 4
// baseline (64.590 us; speedup 1.0000x reference)
//
#include <hip/hip_runtime.h>

#define A_COUNT 24576
#define B_COUNT 32
#define NOBJ 16
#define C_COUNT 21

#define NCH 64                       // anchor chunks in k_match
#define CHUNK (A_COUNT / NCH)        // 384 anchors per k_match block
#define SEG 256                      // anchors per k_fused block
#define NSEG (A_COUNT / SEG)         // 96
#define NB_FUSED (NSEG * B_COUNT)    // 3072
#define F4_PER_BLOCK (SEG * C_COUNT / 4)  // 1344 float4 per k_fused block

// ---- workspace layout (bytes); every slot fully rewritten every call ----
#define WS_BPP 0                         // u64 [B*NOBJ*NCH] = 256 KB
#define WS_LOCP (256 * 1024)             // f32 [NB_FUSED]
#define WS_POSP (256 * 1024 + 16384)     // u32 [NB_FUSED]
#define WS_CLSP (256 * 1024 + 32768)     // f32 [NB_FUSED]

__device__ __forceinline__ unsigned long long pack_key(float iou, int a) {
    unsigned int ib = __float_as_uint(iou);  // iou >= 0 so uint order == float order
    return ((unsigned long long)ib << 32) | (unsigned long long)(0xFFFFFFFFu - (unsigned int)a);
}

__device__ __forceinline__ float iou_pf(float tx0, float ty0, float tx1, float ty1, float at,
                                        float x0, float y0, float x1, float y1, float ap) {
    float lx = fmaxf(tx0, x0), ly = fmaxf(ty0, y0);
    float rx = fminf(tx1, x1), ry = fminf(ty1, y1);
    float w = fmaxf(rx - lx, 0.0f), h = fmaxf(ry - ly, 0.0f);
    float inter = w * h;
    return inter / (at + ap - inter);
}

// Kernel 1: per (chunk, batch) block: each anchor loaded ONCE, 16 IoUs from
// registers, per-truth block argmax (smallest-a tie-break). No atomics.
__global__ __launch_bounds__(256) void k_match(const float4* __restrict__ anchors,
                                               const float4* __restrict__ truths,
                                               unsigned long long* __restrict__ bp_partial) {
    const int ch = blockIdx.x;
    const int b = blockIdx.y;
    const int tid = threadIdx.x;
    __shared__ float4 s_t[NOBJ];
    __shared__ float s_area[NOBJ];
    __shared__ unsigned long long s_part[NOBJ][4];
    if (tid < NOBJ) {
        float4 t = truths[b * NOBJ + tid];
        s_t[tid] = t;
        s_area[tid] = (t.z - t.x) * (t.w - t.y);
    }
    __syncthreads();
    const int a0 = ch * CHUNK + tid;          // always valid (tid < 256 < 384)
    const bool has1 = tid < (CHUNK - 256);    // tid < 128
    const int a1 = a0 + 256;
    float4 an0 = anchors[a0];
    float4 an1 = anchors[has1 ? a1 : a0];
    float q0x0 = an0.x - an0.z * 0.5f, q0y0 = an0.y - an0.w * 0.5f;
    float q0x1 = an0.x + an0.z * 0.5f, q0y1 = an0.y + an0.w * 0.5f;
    float ap0 = (q0x1 - q0x0) * (q0y1 - q0y0);
    float q1x0 = an1.x - an1.z * 0.5f, q1y0 = an1.y - an1.w * 0.5f;
    float q1x1 = an1.x + an1.z * 0.5f, q1y1 = an1.y + an1.w * 0.5f;
    float ap1 = (q1x1 - q1x0) * (q1y1 - q1y0);
#pragma unroll
    for (int n = 0; n < NOBJ; ++n) {
        float4 t = s_t[n];
        float at = s_area[n];
        float iou0 = iou_pf(t.x, t.y, t.z, t.w, at, q0x0, q0y0, q0x1, q0y1, ap0);
        unsigned long long key = pack_key(iou0, a0);
        if (has1) {
            float iou1 = iou_pf(t.x, t.y, t.z, t.w, at, q1x0, q1y0, q1x1, q1y1, ap1);
            unsigned long long k1 = pack_key(iou1, a1);
            key = (k1 > key) ? k1 : key;
        }
#pragma unroll
        for (int s = 32; s >= 1; s >>= 1) {
            unsigned long long o = __shfl_xor(key, s);
            key = (o > key) ? o : key;
        }
        if ((tid & 63) == 0) s_part[n][tid >> 6] = key;
    }
    __syncthreads();
    if (tid < NOBJ) {
        unsigned long long k = s_part[tid][0];
#pragma unroll
        for (int i = 1; i < 4; ++i) k = (s_part[tid][i] > k) ? s_part[tid][i] : k;
        bp_partial[(b * NOBJ + tid) * NCH + ch] = k;
    }
}

__device__ __forceinline__ float sl1(float d) {
    float ad = fabsf(d);
    return (ad < 1.0f) ? 0.5f * d * d : ad - 0.5f;
}

// Kernel 2: fused conf + smooth-L1 + focal. Block owns 256 consecutive anchors
// of one batch; conf lives in LDS only; logits streamed coalesced.
__global__ __launch_bounds__(256) void k_fused(const float4* __restrict__ cls4,
                                               const float4* __restrict__ locp,
                                               const float4* __restrict__ truths,
                                               const float4* __restrict__ anchors,
                                               const int* __restrict__ labels,
                                               const unsigned long long* __restrict__ bp_partial,
                                               float* __restrict__ loc_partial,
                                               unsigned int* __restrict__ pos_partial,
                                               float* __restrict__ cls_partial) {
    const int seg = blockIdx.x;
    const int b = blockIdx.y;
    const int tid = threadIdx.x;
    __shared__ float4 s_t[NOBJ];
    __shared__ float s_area[NOBJ];
    __shared__ int s_lab[NOBJ];
    __shared__ int s_bp[NOBJ];
    __shared__ int s_conf[SEG];
    if (tid < NOBJ) {
        float4 t = truths[b * NOBJ + tid];
        s_t[tid] = t;
        s_area[tid] = (t.z - t.x) * (t.w - t.y);
        s_lab[tid] = labels[b * NOBJ + tid];
    }
    {   // reduce 64 match partials per truth: 16 groups x 16 lanes
        const int g = tid >> 4, l = tid & 15;
        const unsigned long long* p = &bp_partial[(b * NOBJ + g) * NCH];
        unsigned long long k = p[l];
        unsigned long long k1 = p[l + 16]; k = (k1 > k) ? k1 : k;
        unsigned long long k2 = p[l + 32]; k = (k2 > k) ? k2 : k;
        unsigned long long k3 = p[l + 48]; k = (k3 > k) ? k3 : k;
#pragma unroll
        for (int s = 8; s >= 1; s >>= 1) {
            unsigned long long o = __shfl_xor(k, s);
            k = (o > k) ? o : k;
        }
        if (l == 0) {
            unsigned int ia = 0xFFFFFFFFu - (unsigned int)(k & 0xFFFFFFFFull);
            s_bp[g] = (ia >= A_COUNT) ? -1 : (int)ia;
        }
    }
    __syncthreads();
    const int a = seg * SEG + tid;
    float4 an = anchors[a];
    float ax0 = an.x - an.z * 0.5f, ay0 = an.y - an.w * 0.5f;
    float ax1 = an.x + an.z * 0.5f, ay1 = an.y + an.w * 0.5f;
    float area_p = (ax1 - ax0) * (ay1 - ay0);
    float best = -1.0f;
    int idx = 0;
#pragma unroll
    for (int n = 0; n < NOBJ; ++n) {
        float iou = iou_pf(s_t[n].x, s_t[n].y, s_t[n].z, s_t[n].w, s_area[n],
                           ax0, ay0, ax1, ay1, area_p);
        if (iou > best) { best = iou; idx = n; }   // first-occurrence argmax over n
    }
#pragma unroll
    for (int n = 0; n < NOBJ; ++n) {
        if (s_bp[n] == a) { best = 2.0f; idx = n; }  // forced match, last n wins
    }
    const int conf = (best < 0.5f) ? 0 : s_lab[idx];
    s_conf[tid] = conf;

    float loc_l = 0.0f;
    unsigned int pos = 0;
    if (conf > 0) {
        pos = 1;
        float4 t = s_t[idx];
        float gx = ((t.x + t.z) * 0.5f - an.x) / (0.1f * an.z);
        float gy = ((t.y + t.w) * 0.5f - an.y) / (0.1f * an.w);
        float gw = __logf((t.z - t.x) / an.z) * 5.0f;
        float gh = __logf((t.w - t.y) / an.w) * 5.0f;
        float4 lp = locp[b * A_COUNT + a];
        loc_l = sl1(lp.x - gx) + sl1(lp.y - gy) + sl1(lp.z - gw) + sl1(lp.w - gh);
    }
    __syncthreads();

    // focal loss over this block's 256*21 logits, coalesced float4 stream
    const float4* cp4 = cls4 + (size_t)b * (A_COUNT * C_COUNT / 4) + (size_t)seg * F4_PER_BLOCK;
    float cls_l = 0.0f;
    for (int i = tid; i < F4_PER_BLOCK; i += 256) {
        float4 x4 = cp4[i];
        int f = i * 4;
        int d = f / 21;
        int r = f - d * 21;
        float xs[4] = {x4.x, x4.y, x4.z, x4.w};
#pragma unroll
        for (int j = 0; j < 4; ++j) {
            float x = xs[j];
            if (r != 0) {
                bool t = (s_conf[d] == r);
                float e = __expf(-fabsf(x));
                float q = __builtin_amdgcn_rcpf(1.0f + e);  // sigmoid(|x|)
                float p = (x >= 0.0f) ? q : 1.0f - q;       // sigmoid(x)
                float pt = t ? p : (1.0f - p);
                float om = 1.0f - pt;
                float w = om * om * (t ? 0.25f : 0.75f);
                float bce = fmaxf(x, 0.0f) - (t ? x : 0.0f) + __logf(1.0f + e);
                cls_l += w * bce;
            }
            ++r;
            if (r == 21) { r = 0; ++d; }
        }
    }

    // block reduction -> one partial per block
#pragma unroll
    for (int s = 32; s >= 1; s >>= 1) {
        cls_l += __shfl_xor(cls_l, s);
        loc_l += __shfl_xor(loc_l, s);
        pos += __shfl_xor(pos, s);
    }
    __shared__ float s_cl[4], s_ll[4];
    __shared__ unsigned int s_pp[4];
    if ((tid & 63) == 0) {
        s_cl[tid >> 6] = cls_l;
        s_ll[tid >> 6] = loc_l;
        s_pp[tid >> 6] = pos;
    }
    __syncthreads();
    if (tid == 0) {
        int bid = b * NSEG + seg;
        cls_partial[bid] = s_cl[0] + s_cl[1] + s_cl[2] + s_cl[3];
        loc_partial[bid] = s_ll[0] + s_ll[1] + s_ll[2] + s_ll[3];
        pos_partial[bid] = s_pp[0] + s_pp[1] + s_pp[2] + s_pp[3];
    }
}

// Kernel 3: deterministic final reduction in double.
__global__ __launch_bounds__(256) void k_final(const float* __restrict__ loc_partial,
                                               const unsigned int* __restrict__ pos_partial,
                                               const float* __restrict__ cls_partial,
                                               float* __restrict__ out) {
    double loc = 0.0, clsv = 0.0;
    unsigned int pos = 0;
    for (int i = threadIdx.x; i < NB_FUSED; i += 256) {
        loc += (double)loc_partial[i];
        clsv += (double)cls_partial[i];
        pos += pos_partial[i];
    }
#pragma unroll
    for (int s = 32; s >= 1; s >>= 1) {
        loc += __shfl_xor(loc, s);
        clsv += __shfl_xor(clsv, s);
        pos += __shfl_xor(pos, s);
    }
    __shared__ double s_l[4], s_c[4];
    __shared__ unsigned int s_p[4];
    if ((threadIdx.x & 63) == 0) {
        s_l[threadIdx.x >> 6] = loc;
        s_c[threadIdx.x >> 6] = clsv;
        s_p[threadIdx.x >> 6] = pos;
    }
    __syncthreads();
    if (threadIdx.x == 0) {
        double l = s_l[0] + s_l[1] + s_l[2] + s_l[3];
        double c = s_c[0] + s_c[1] + s_c[2] + s_c[3];
        float n = (float)(s_p[0] + s_p[1] + s_p[2] + s_p[3]);
        float cf = (float)c / n;
        float lf = (float)l / n;
        out[0] = cf;
        out[1] = lf;
        out[2] = cf + lf;
    }
}

extern "C" void kernel_launch(void* const* d_in, const int* in_sizes, int n_in,
                              void* d_out, int out_size, void* d_ws, size_t ws_size,
                              hipStream_t stream) {
    const float4* cls4 = (const float4*)d_in[0];
    const float4* locp = (const float4*)d_in[1];
    const float4* truths = (const float4*)d_in[2];
    const float4* anchors = (const float4*)d_in[3];
    const int* labels = (const int*)d_in[4];

    char* ws = (char*)d_ws;
    unsigned long long* bp_partial = (unsigned long long*)(ws + WS_BPP);
    float* loc_partial = (float*)(ws + WS_LOCP);
    unsigned int* pos_partial = (unsigned int*)(ws + WS_POSP);
    float* cls_partial = (float*)(ws + WS_CLSP);

    k_match<<<dim3(NCH, B_COUNT), 256, 0, stream>>>(anchors, truths, bp_partial);
    k_fused<<<dim3(NSEG, B_COUNT), 256, 0, stream>>>(cls4, locp, truths, anchors, labels,
                                                     bp_partial, loc_partial, pos_partial, cls_partial);
    k_final<<<1, 256, 0, stream>>>(loc_partial, pos_partial, cls_partial, (float*)d_out);
}

// Round 5
// 52.323 us; speedup vs baseline: 1.2345x; 1.2345x over previous
//
#include <hip/hip_runtime.h>

#define A_COUNT 24576
#define B_COUNT 32
#define NOBJ 16
#define C_COUNT 21

#define NCH 64                       // anchor chunks in k_match
#define CHUNK (A_COUNT / NCH)        // 384 anchors per k_match block
#define NSEG (A_COUNT / 256)         // 96 k_conf blocks per batch
#define NB_CONF (NSEG * B_COUNT)     // 3072
#define NB_FOCAL 2048
#define TOTAL4 (B_COUNT * A_COUNT * C_COUNT / 4)  // 4128768

// ---- workspace layout (bytes); every slot fully rewritten every call ----
#define WS_BPP 0                     // u64 [B*NOBJ*NCH] = 256 KB
#define WS_CLSM (256 * 1024)         // f32 [NB_FOCAL]  main focal partials
#define WS_LOCP (256 * 1024 + 8192)  // f32 [NB_CONF]
#define WS_POSP (256 * 1024 + 8192 + 12288)          // u32 [NB_CONF]
#define WS_CORR (256 * 1024 + 8192 + 12288 + 12288)  // f32 [NB_CONF]

__device__ __forceinline__ unsigned long long pack_key(float iou, int a) {
    unsigned int ib = __float_as_uint(iou);  // iou >= 0 so uint order == float order
    return ((unsigned long long)ib << 32) | (unsigned long long)(0xFFFFFFFFu - (unsigned int)a);
}

__device__ __forceinline__ float iou_pf(float tx0, float ty0, float tx1, float ty1, float at,
                                        float x0, float y0, float x1, float y1, float ap) {
    float lx = fmaxf(tx0, x0), ly = fmaxf(ty0, y0);
    float rx = fminf(tx1, x1), ry = fminf(ty1, y1);
    float w = fmaxf(rx - lx, 0.0f), h = fmaxf(ry - ly, 0.0f);
    float inter = w * h;
    return inter / (at + ap - inter);
}

// Kernel 1: pure-stream focal main term: for ALL non-background logits,
// 0.75 * p^2 * ln(1+e^x)  (t=0 form; positives corrected exactly in k_conf).
// No conf dependency, no LDS in hot loop, coalesced float4 walk.
__global__ __launch_bounds__(256) void k_focal(const float4* __restrict__ cls4,
                                               float* __restrict__ cls_partial) {
    const int tid = threadIdx.x;
    float acc = 0.0f;
    int i = blockIdx.x * 256 + tid;
    unsigned int f = (unsigned int)i * 4u;
    unsigned int d = f / 21u;
    int r = (int)(f - d * 21u);
    const int stride = NB_FOCAL * 256;
    for (; i < TOTAL4; i += stride) {
        float4 x4 = cls4[i];
        float xs[4] = {x4.x, x4.y, x4.z, x4.w};
#pragma unroll
        for (int j = 0; j < 4; ++j) {
            float x = xs[j];
            int rr = r + j;                         // in [0,23]; background iff 0 or 21
            float E = __expf(x);                    // e^x (|x|<~6, no overflow)
            float den = 1.0f + E;
            float s = __builtin_amdgcn_rcpf(den);   // 1-p
            float p = E * s;                        // sigmoid(x)
            float L = __logf(den);                  // ln(1+e^x)
            float t2 = p * p * L;
            float m = (rr == 0 || rr == 21) ? 0.0f : 0.75f;
            acc = fmaf(t2, m, acc);
        }
        r += 8; if (r >= 21) r -= 21;               // (stride*4) mod 21 == 8
    }
#pragma unroll
    for (int s = 32; s >= 1; s >>= 1) acc += __shfl_xor(acc, s);
    __shared__ float s_acc[4];
    if ((tid & 63) == 0) s_acc[tid >> 6] = acc;
    __syncthreads();
    if (tid == 0) cls_partial[blockIdx.x] = s_acc[0] + s_acc[1] + s_acc[2] + s_acc[3];
}

// Kernel 2: per (chunk, batch): each anchor loaded once, LDS-tree argmax per
// truth (8 truths per half to keep LDS at 16 KB). No atomics, no u64 butterflies.
__global__ __launch_bounds__(256) void k_match(const float4* __restrict__ anchors,
                                               const float4* __restrict__ truths,
                                               unsigned long long* __restrict__ bp_partial) {
    const int ch = blockIdx.x;
    const int b = blockIdx.y;
    const int tid = threadIdx.x;
    __shared__ float4 s_t[NOBJ];
    __shared__ float s_area[NOBJ];
    __shared__ unsigned long long s_keys[8][256];
    if (tid < NOBJ) {
        float4 t = truths[b * NOBJ + tid];
        s_t[tid] = t;
        s_area[tid] = (t.z - t.x) * (t.w - t.y);
    }
    __syncthreads();
    const int a0 = ch * CHUNK + tid;
    const bool has1 = tid < (CHUNK - 256);
    const int a1 = a0 + 256;
    float4 an0 = anchors[a0];
    float4 an1 = anchors[has1 ? a1 : a0];
    float q0x0 = an0.x - an0.z * 0.5f, q0y0 = an0.y - an0.w * 0.5f;
    float q0x1 = an0.x + an0.z * 0.5f, q0y1 = an0.y + an0.w * 0.5f;
    float ap0 = (q0x1 - q0x0) * (q0y1 - q0y0);
    float q1x0 = an1.x - an1.z * 0.5f, q1y0 = an1.y - an1.w * 0.5f;
    float q1x1 = an1.x + an1.z * 0.5f, q1y1 = an1.y + an1.w * 0.5f;
    float ap1 = (q1x1 - q1x0) * (q1y1 - q1y0);
#pragma unroll
    for (int half = 0; half < 2; ++half) {
#pragma unroll
        for (int n = 0; n < 8; ++n) {
            const int nt = half * 8 + n;
            float4 t = s_t[nt];
            float at = s_area[nt];
            float iou0 = iou_pf(t.x, t.y, t.z, t.w, at, q0x0, q0y0, q0x1, q0y1, ap0);
            unsigned long long key = pack_key(iou0, a0);
            if (has1) {
                float iou1 = iou_pf(t.x, t.y, t.z, t.w, at, q1x0, q1y0, q1x1, q1y1, ap1);
                unsigned long long k1 = pack_key(iou1, a1);
                key = (k1 > key) ? k1 : key;
            }
            s_keys[n][tid] = key;
        }
        __syncthreads();
        if (tid < 128) {
            const int g = tid >> 4, l = tid & 15;
            unsigned long long k = s_keys[g][l];
#pragma unroll
            for (int kk = 1; kk < 16; ++kk) {
                unsigned long long v = s_keys[g][l + 16 * kk];
                k = (v > k) ? v : k;
            }
#pragma unroll
            for (int s = 8; s >= 1; s >>= 1) {
                unsigned long long o = __shfl_xor(k, s);
                k = (o > k) ? o : k;
            }
            if (l == 0) bp_partial[(b * NOBJ + half * 8 + g) * NCH + ch] = k;
        }
        __syncthreads();
    }
}

__device__ __forceinline__ float sl1(float d) {
    float ad = fabsf(d);
    return (ad < 1.0f) ? 0.5f * d * d : ad - 0.5f;
}

// Kernel 3: per-anchor match + forced override + smooth-L1 + focal correction
// for positive anchors (exact replacement of the t=0 term by the t=1 term).
__global__ __launch_bounds__(256) void k_conf(const float* __restrict__ cls,
                                              const float4* __restrict__ locp,
                                              const float4* __restrict__ truths,
                                              const float4* __restrict__ anchors,
                                              const int* __restrict__ labels,
                                              const unsigned long long* __restrict__ bp_partial,
                                              float* __restrict__ loc_partial,
                                              unsigned int* __restrict__ pos_partial,
                                              float* __restrict__ corr_partial) {
    const int seg = blockIdx.x;
    const int b = blockIdx.y;
    const int tid = threadIdx.x;
    __shared__ float4 s_t[NOBJ];
    __shared__ float s_area[NOBJ];
    __shared__ int s_lab[NOBJ];
    __shared__ int s_bp[NOBJ];
    if (tid < NOBJ) {
        float4 t = truths[b * NOBJ + tid];
        s_t[tid] = t;
        s_area[tid] = (t.z - t.x) * (t.w - t.y);
        s_lab[tid] = labels[b * NOBJ + tid];
    }
    {   // reduce 64 match partials per truth: 16 groups x 16 lanes
        const int g = tid >> 4, l = tid & 15;
        const unsigned long long* pp = &bp_partial[(b * NOBJ + g) * NCH];
        unsigned long long k = pp[l];
        unsigned long long k1 = pp[l + 16]; k = (k1 > k) ? k1 : k;
        unsigned long long k2 = pp[l + 32]; k = (k2 > k) ? k2 : k;
        unsigned long long k3 = pp[l + 48]; k = (k3 > k) ? k3 : k;
#pragma unroll
        for (int s = 8; s >= 1; s >>= 1) {
            unsigned long long o = __shfl_xor(k, s);
            k = (o > k) ? o : k;
        }
        if (l == 0) {
            unsigned int ia = 0xFFFFFFFFu - (unsigned int)(k & 0xFFFFFFFFull);
            s_bp[g] = (ia >= A_COUNT) ? -1 : (int)ia;
        }
    }
    __syncthreads();
    const int a = seg * 256 + tid;
    float4 an = anchors[a];
    float ax0 = an.x - an.z * 0.5f, ay0 = an.y - an.w * 0.5f;
    float ax1 = an.x + an.z * 0.5f, ay1 = an.y + an.w * 0.5f;
    float area_p = (ax1 - ax0) * (ay1 - ay0);
    float best = -1.0f;
    int idx = 0;
#pragma unroll
    for (int n = 0; n < NOBJ; ++n) {
        float iou = iou_pf(s_t[n].x, s_t[n].y, s_t[n].z, s_t[n].w, s_area[n],
                           ax0, ay0, ax1, ay1, area_p);
        if (iou > best) { best = iou; idx = n; }   // first-occurrence argmax over n
    }
#pragma unroll
    for (int n = 0; n < NOBJ; ++n) {
        if (s_bp[n] == a) { best = 2.0f; idx = n; }  // forced match, last n wins
    }
    const int conf = (best < 0.5f) ? 0 : s_lab[idx];

    float loc_l = 0.0f, corr = 0.0f;
    unsigned int pos = 0;
    if (conf > 0) {
        pos = 1;
        float4 t = s_t[idx];
        float gx = ((t.x + t.z) * 0.5f - an.x) / (0.1f * an.z);
        float gy = ((t.y + t.w) * 0.5f - an.y) / (0.1f * an.w);
        float gw = __logf((t.z - t.x) / an.z) * 5.0f;
        float gh = __logf((t.w - t.y) / an.w) * 5.0f;
        float4 lp = locp[b * A_COUNT + a];
        loc_l = sl1(lp.x - gx) + sl1(lp.y - gy) + sl1(lp.z - gw) + sl1(lp.w - gh);
        // exact focal correction at the matched class column:
        // add 0.25*(1-p)^2*(-ln p) and remove the 0.75*p^2*ln(1+e^x) main term
        float x = cls[(size_t)(b * A_COUNT + a) * C_COUNT + conf];
        float E = __expf(x);
        float den = 1.0f + E;
        float s = __builtin_amdgcn_rcpf(den);   // 1-p
        float p = E * s;
        float L = __logf(den);                  // ln(1+e^x); -ln p = L - x
        corr = 0.25f * s * s * (L - x) - 0.75f * p * p * L;
    }

#pragma unroll
    for (int s = 32; s >= 1; s >>= 1) {
        loc_l += __shfl_xor(loc_l, s);
        corr += __shfl_xor(corr, s);
        pos += __shfl_xor(pos, s);
    }
    __shared__ float s_ll[4], s_cr[4];
    __shared__ unsigned int s_pp[4];
    if ((tid & 63) == 0) {
        s_ll[tid >> 6] = loc_l;
        s_cr[tid >> 6] = corr;
        s_pp[tid >> 6] = pos;
    }
    __syncthreads();
    if (tid == 0) {
        int bid = b * NSEG + seg;
        loc_partial[bid] = s_ll[0] + s_ll[1] + s_ll[2] + s_ll[3];
        corr_partial[bid] = s_cr[0] + s_cr[1] + s_cr[2] + s_cr[3];
        pos_partial[bid] = s_pp[0] + s_pp[1] + s_pp[2] + s_pp[3];
    }
}

// Kernel 4: deterministic final reduction in double.
__global__ __launch_bounds__(256) void k_final(const float* __restrict__ loc_partial,
                                               const unsigned int* __restrict__ pos_partial,
                                               const float* __restrict__ corr_partial,
                                               const float* __restrict__ cls_partial,
                                               float* __restrict__ out) {
    double loc = 0.0, clsv = 0.0;
    unsigned int pos = 0;
    for (int i = threadIdx.x; i < NB_CONF; i += 256) {
        loc += (double)loc_partial[i];
        clsv += (double)corr_partial[i];
        pos += pos_partial[i];
    }
    for (int i = threadIdx.x; i < NB_FOCAL; i += 256) clsv += (double)cls_partial[i];
#pragma unroll
    for (int s = 32; s >= 1; s >>= 1) {
        loc += __shfl_xor(loc, s);
        clsv += __shfl_xor(clsv, s);
        pos += __shfl_xor(pos, s);
    }
    __shared__ double s_l[4], s_c[4];
    __shared__ unsigned int s_p[4];
    if ((threadIdx.x & 63) == 0) {
        s_l[threadIdx.x >> 6] = loc;
        s_c[threadIdx.x >> 6] = clsv;
        s_p[threadIdx.x >> 6] = pos;
    }
    __syncthreads();
    if (threadIdx.x == 0) {
        double l = s_l[0] + s_l[1] + s_l[2] + s_l[3];
        double c = s_c[0] + s_c[1] + s_c[2] + s_c[3];
        float n = (float)(s_p[0] + s_p[1] + s_p[2] + s_p[3]);
        float cf = (float)c / n;
        float lf = (float)l / n;
        out[0] = cf;
        out[1] = lf;
        out[2] = cf + lf;
    }
}

extern "C" void kernel_launch(void* const* d_in, const int* in_sizes, int n_in,
                              void* d_out, int out_size, void* d_ws, size_t ws_size,
                              hipStream_t stream) {
    const float* cls = (const float*)d_in[0];
    const float4* locp = (const float4*)d_in[1];
    const float4* truths = (const float4*)d_in[2];
    const float4* anchors = (const float4*)d_in[3];
    const int* labels = (const int*)d_in[4];

    char* ws = (char*)d_ws;
    unsigned long long* bp_partial = (unsigned long long*)(ws + WS_BPP);
    float* cls_partial = (float*)(ws + WS_CLSM);
    float* loc_partial = (float*)(ws + WS_LOCP);
    unsigned int* pos_partial = (unsigned int*)(ws + WS_POSP);
    float* corr_partial = (float*)(ws + WS_CORR);

    k_focal<<<NB_FOCAL, 256, 0, stream>>>((const float4*)cls, cls_partial);
    k_match<<<dim3(NCH, B_COUNT), 256, 0, stream>>>(anchors, truths, bp_partial);
    k_conf<<<dim3(NSEG, B_COUNT), 256, 0, stream>>>(cls, locp, truths, anchors, labels,
                                                    bp_partial, loc_partial, pos_partial, corr_partial);
    k_final<<<1, 256, 0, stream>>>(loc_partial, pos_partial, corr_partial, cls_partial, (float*)d_out);
}